// Round 18
// baseline (283.271 us; speedup 1.0000x reference)
//
#include <hip/hip_runtime.h>

#define DIN 256
#define DH  256
#define DOUT 128

typedef __attribute__((ext_vector_type(8))) short bf16x8;
typedef __attribute__((ext_vector_type(4))) float f32x4;
typedef __attribute__((ext_vector_type(2))) float f32x2;
typedef __attribute__((ext_vector_type(4))) unsigned short ushort4v;
typedef __attribute__((ext_vector_type(8))) unsigned short ushort8v;
typedef __attribute__((ext_vector_type(4))) unsigned int uint4v;

static __device__ __forceinline__ unsigned short f2bf(float x) {
    unsigned u = __float_as_uint(x);
    u += 0x7fffu + ((u >> 16) & 1u);          // round-to-nearest-even
    return (unsigned short)(u >> 16);
}
static __device__ __forceinline__ float bf2f(unsigned short h) {
    return __uint_as_float(((unsigned)h) << 16);
}

static __device__ __forceinline__ void gload16(const unsigned short* g, void* l) {
    __builtin_amdgcn_global_load_lds(
        (const __attribute__((address_space(1))) unsigned int*)g,
        (__attribute__((address_space(3))) unsigned int*)l,
        16, 0, 0);
}

// cvt work unit: thread handles f32x4 chunks i and i+ncHalf (MLP=2, coalesced)
static __device__ __forceinline__ void cvt_unit(const float* __restrict__ feat,
                                                unsigned short* __restrict__ featb,
                                                unsigned int* __restrict__ feat8,
                                                long long i, long long ncHalf) {
    long long i2 = i + ncHalf;
    f32x4 v0 = __builtin_nontemporal_load((const f32x4*)feat + i);
    f32x4 v1 = __builtin_nontemporal_load((const f32x4*)feat + i2);
    ushort4v o0, o1;
    o0[0] = f2bf(v0[0]); o0[1] = f2bf(v0[1]); o0[2] = f2bf(v0[2]); o0[3] = f2bf(v0[3]);
    o1[0] = f2bf(v1[0]); o1[1] = f2bf(v1[1]); o1[2] = f2bf(v1[2]); o1[3] = f2bf(v1[3]);
    *((ushort4v*)featb + i)  = o0;          // plain: cached for gemm1
    *((ushort4v*)featb + i2) = o1;
    int u0 = __builtin_amdgcn_cvt_pk_fp8_f32(v0[0], v0[1], 0, 0);
    u0     = __builtin_amdgcn_cvt_pk_fp8_f32(v0[2], v0[3], u0, 1);
    int u1 = __builtin_amdgcn_cvt_pk_fp8_f32(v1[0], v1[1], 0, 0);
    u1     = __builtin_amdgcn_cvt_pk_fp8_f32(v1[2], v1[3], u1, 1);
    feat8[i]  = (unsigned)u0;               // plain: must stay L2/L3-hot for gather
    feat8[i2] = (unsigned)u1;
}

// ==== A: degree-count blocks Bresenham-interleaved among cvt[0, bCvtA) blocks ====
__global__ void countcvt_kernel(const int* __restrict__ dst, int* __restrict__ cnt, int E, int bCnt,
                                const float* __restrict__ feat, unsigned short* __restrict__ featb,
                                unsigned int* __restrict__ feat8, long long ncHalf, int nA) {
    int b = blockIdx.x;
    int t0 = (int)((long long)b * bCnt / nA);
    int t1 = (int)((long long)(b + 1) * bCnt / nA);
    if (t1 > t0) {
        int e = t0 * 256 + threadIdx.x;
        if (e < E) atomicAdd(&cnt[dst[e]], 1);
    } else {
        long long i = (long long)(b - t0) * 256 + threadIdx.x;
        if (i < ncHalf) cvt_unit(feat, featb, feat8, i, ncHalf);
    }
}

// ==== single-pass scan with decoupled lookback (98 blocks, all co-resident) ====
// writes offsets AND initializes the fill-cursor (cnt)
__global__ void scan_lookback_kernel(int* __restrict__ cnt, int* __restrict__ status,
                                     int* __restrict__ aggbuf, int* __restrict__ inclbuf,
                                     int* __restrict__ off, int N, int E, int nb) {
    __shared__ int sdata[256];
    __shared__ int sbase;
    int b = blockIdx.x, t = threadIdx.x;
    int base = b * 1024;
    int vals[4]; int local = 0;
#pragma unroll
    for (int j = 0; j < 4; ++j) {
        int i = base + t * 4 + j;
        vals[j] = (i < N) ? cnt[i] : 0;
        local += vals[j];
    }
    sdata[t] = local; __syncthreads();
    for (int o = 1; o < 256; o <<= 1) {
        int y = (t >= o) ? sdata[t - o] : 0;
        __syncthreads();
        sdata[t] += y;
        __syncthreads();
    }
    int total = sdata[255];

    if (t == 0) {
        aggbuf[b] = total;
        __threadfence();
        atomicExch(&status[b], 1);          // aggregate ready
        int acc = 0;
        for (int j = b - 1; j >= 0; --j) {
            int s;
            while ((s = atomicAdd(&status[j], 0)) == 0) { }
            __threadfence();
            if (s == 2) { acc += inclbuf[j]; break; }
            acc += aggbuf[j];
        }
        inclbuf[b] = acc + total;
        __threadfence();
        atomicExch(&status[b], 2);          // inclusive ready
        sbase = acc;
    }
    __syncthreads();
    int base0 = sbase;

    int run = sdata[t] - local + base0;     // exclusive prefix for this thread
#pragma unroll
    for (int j = 0; j < 4; ++j) {
        int i = base + t * 4 + j;
        if (i < N) { off[i] = run; cnt[i] = run; }   // cnt becomes cursor
        run += vals[j];
    }
    if (b == 0 && t == 0) off[N] = E;
}

// ==== B: fill-csr blocks Bresenham-interleaved among cvt[bCvtA, end) + wtrans blocks ====
__global__ void fillcvt_kernel(const int* __restrict__ src, const int* __restrict__ dst,
                               int* __restrict__ cursor, int* __restrict__ csr, int E, int bFill,
                               const float* __restrict__ feat, unsigned short* __restrict__ featb,
                               unsigned int* __restrict__ feat8, long long ncHalf,
                               int cvtOff, int bCvtB,
                               const float* __restrict__ w_self1, const float* __restrict__ w_neigh1,
                               const float* __restrict__ w_self2, const float* __restrict__ w_neigh2,
                               unsigned short* __restrict__ ws1t, unsigned short* __restrict__ wn1t,
                               unsigned short* __restrict__ wcat, int nB) {
    int b = blockIdx.x;
    int t0 = (int)((long long)b * bFill / nB);
    int t1 = (int)((long long)(b + 1) * bFill / nB);
    if (t1 > t0) {
        int e = t0 * 256 + threadIdx.x;
        if (e < E) {
            int d = dst[e];
            int p = atomicAdd(&cursor[d], 1);
            csr[p] = src[e];
        }
    } else {
        int j = b - t0;
        if (j < bCvtB) {
            long long i = (long long)(cvtOff + j) * 256 + threadIdx.x;
            if (i < ncHalf) cvt_unit(feat, featb, feat8, i, ncHalf);
        } else {
            int idx = (j - bCvtB) * 256 + threadIdx.x;
            if (idx < 65536) {                      // ws1t[n][k] = w_self1[k][n]
                int nn = idx >> 8, k = idx & 255;
                ws1t[idx] = f2bf(w_self1[k * 256 + nn]);
            } else if (idx < 131072) {              // wn1t
                int jj = idx - 65536; int nn = jj >> 8, k = jj & 255;
                wn1t[jj] = f2bf(w_neigh1[k * 256 + nn]);
            } else if (idx < 163840) {              // wcat rows 0..127 = wn2^T
                int jj = idx - 131072; int nn = jj >> 8, k = jj & 255;
                wcat[jj] = f2bf(w_neigh2[k * 128 + nn]);
            } else if (idx < 196608) {              // wcat rows 128..255 = ws2^T
                int jj = idx - 163840; int nn = jj >> 8, k = jj & 255;
                wcat[32768 + jj] = f2bf(w_self2[k * 128 + nn]);
            }
        }
    }
}

// ===== gather-mean D=256 from fp8: 4 rows per load (16 lanes each, 16B/lane) =====
__global__ void gather_mean256_kernel(const unsigned int* __restrict__ feat8, const int* __restrict__ off,
                                      const int* __restrict__ csr, unsigned short* __restrict__ agg, int N) {
    int wid  = (int)((blockIdx.x * (long long)blockDim.x + threadIdx.x) >> 6);
    int lane = threadIdx.x & 63;
    if (wid >= N) return;
    int start = off[wid], end = off[wid + 1];
    const int g   = lane >> 4;
    const int cl  = lane & 15;
    float a[16] = {};
    int e = start;
    for (; e + 7 < end; e += 8) {
        int s0 = csr[e + g], s1 = csr[e + 4 + g];
        uint4v v0 = *(const uint4v*)(feat8 + (long long)s0 * 64 + cl * 4);
        uint4v v1 = *(const uint4v*)(feat8 + (long long)s1 * 64 + cl * 4);
#pragma unroll
        for (int d = 0; d < 4; ++d) {
            f32x2 p0 = __builtin_amdgcn_cvt_pk_f32_fp8((int)v0[d], false);
            f32x2 p1 = __builtin_amdgcn_cvt_pk_f32_fp8((int)v0[d], true);
            f32x2 q0 = __builtin_amdgcn_cvt_pk_f32_fp8((int)v1[d], false);
            f32x2 q1 = __builtin_amdgcn_cvt_pk_f32_fp8((int)v1[d], true);
            a[d * 4 + 0] += p0[0] + q0[0];
            a[d * 4 + 1] += p0[1] + q0[1];
            a[d * 4 + 2] += p1[0] + q1[0];
            a[d * 4 + 3] += p1[1] + q1[1];
        }
    }
    for (; e < end; e += 4) {
        int idx = e + g;
        if (idx < end) {
            int s = csr[idx];
            uint4v v = *(const uint4v*)(feat8 + (long long)s * 64 + cl * 4);
#pragma unroll
            for (int d = 0; d < 4; ++d) {
                f32x2 p0 = __builtin_amdgcn_cvt_pk_f32_fp8((int)v[d], false);
                f32x2 p1 = __builtin_amdgcn_cvt_pk_f32_fp8((int)v[d], true);
                a[d * 4 + 0] += p0[0];
                a[d * 4 + 1] += p0[1];
                a[d * 4 + 2] += p1[0];
                a[d * 4 + 3] += p1[1];
            }
        }
    }
#pragma unroll
    for (int j = 0; j < 16; ++j) {
        a[j] += __shfl_xor(a[j], 16);
        a[j] += __shfl_xor(a[j], 32);
    }
    if (g == 0) {
        float inv = 1.0f / (float)max(end - start, 1);
        ushort8v o0, o1;
#pragma unroll
        for (int j = 0; j < 8; ++j) { o0[j] = f2bf(a[j] * inv); o1[j] = f2bf(a[8 + j] * inv); }
        unsigned short* dstp = agg + (long long)wid * 256 + cl * 16;
        *(ushort8v*)dstp       = o0;   // plain store: agg read by gemm1 next
        *(ushort8v*)(dstp + 8) = o1;
    }
}

// ================= GEMM 1: h1 = relu(feat@Ws1 + agg@Wn1 + b1) =================
__global__ __launch_bounds__(512)
void gemm1_kernel(const unsigned short* __restrict__ A,  const unsigned short* __restrict__ WT,
                  const unsigned short* __restrict__ A2, const unsigned short* __restrict__ WT2,
                  const float* __restrict__ bias, unsigned short* __restrict__ C, int M)
{
    const int K = 256;
    __shared__ __align__(16) char lds[2][24576];   // A: [0,8192)  B: [8192,24576)

    const int tid = threadIdx.x;
    const int wid = tid >> 6, lane = tid & 63;
    const int l15 = lane & 15, lg = lane >> 4;
    const int wr = wid >> 2, wc = wid & 3;
    const int row0 = blockIdx.x * 128;

    long long asrc; int adst;
    {
        int c = tid, r = c >> 2, s = c & 3;
        int kc = s ^ ((r >> 1) & 3);
        asrc = (long long)min(row0 + r, M - 1) * K + kc * 8;
        adst = c * 16;
    }
    long long bsrc[2]; int bdst[2];
#pragma unroll
    for (int i = 0; i < 2; ++i) {
        int c = wid * 128 + i * 64 + lane, r = c >> 2, s = c & 3;
        int kc = s ^ ((r >> 1) & 3);
        bsrc[i] = (long long)r * K + kc * 8;
        bdst[i] = 8192 + c * 16;
    }

    const int slot = (lg ^ ((l15 >> 1) & 3)) * 16;
    int aoff[4], boff[4];
#pragma unroll
    for (int m = 0; m < 4; ++m) aoff[m] = (wr * 64 + m * 16 + l15) * 64 + slot;
#pragma unroll
    for (int n = 0; n < 4; ++n) boff[n] = 8192 + (wc * 64 + n * 16 + l15) * 64 + slot;

    f32x4 acc[4][4] = {};

    auto stage = [&](int buf, int t) {
        const unsigned short* Ap = (t >= 8) ? A2 : A;
        const unsigned short* Wp = (t >= 8) ? WT2 : WT;
        int k0 = (t & 7) * 32;
        gload16(Ap + asrc + k0, &lds[buf][adst]);
        gload16(Wp + bsrc[0] + k0, &lds[buf][bdst[0]]);
        gload16(Wp + bsrc[1] + k0, &lds[buf][bdst[1]]);
    };

    stage(0, 0);
    __syncthreads();

    for (int t = 0; t < 16; ++t) {
        const int cur = t & 1;
        if (t + 1 < 16) stage(cur ^ 1, t + 1);
        const char* L = lds[cur];
        bf16x8 af[4], bfr[4];
#pragma unroll
        for (int m = 0; m < 4; ++m) af[m]  = *(const bf16x8*)(L + aoff[m]);
#pragma unroll
        for (int n = 0; n < 4; ++n) bfr[n] = *(const bf16x8*)(L + boff[n]);
#pragma unroll
        for (int m = 0; m < 4; ++m)
#pragma unroll
            for (int n = 0; n < 4; ++n)
                acc[m][n] = __builtin_amdgcn_mfma_f32_16x16x32_bf16(af[m], bfr[n], acc[m][n], 0, 0, 0);
        __syncthreads();
    }

#pragma unroll
    for (int m = 0; m < 4; ++m) {
#pragma unroll
        for (int rr = 0; rr < 4; ++rr) {
            int grow = row0 + wr * 64 + m * 16 + lg * 4 + rr;
            if (grow >= M) continue;
#pragma unroll
            for (int n = 0; n < 4; ++n) {
                int gcol = wc * 64 + n * 16 + l15;
                float v = fmaxf(acc[m][n][rr] + bias[gcol], 0.f);
                C[(long long)grow * 256 + gcol] = f2bf(v);
            }
        }
    }
}

// ====== GEMM 23: [p2 | self2+b2] = h1 @ wcat^T  (single K=256 pass, split epilogue) ======
__global__ __launch_bounds__(512)
void gemm23_kernel(const unsigned short* __restrict__ A, const unsigned short* __restrict__ WT,
                   const float* __restrict__ b2,
                   unsigned short* __restrict__ p2, unsigned short* __restrict__ self2, int M)
{
    const int K = 256;
    __shared__ __align__(16) char lds[2][24576];   // A: [0,8192)  B: [8192,24576)

    const int tid = threadIdx.x;
    const int wid = tid >> 6, lane = tid & 63;
    const int l15 = lane & 15, lg = lane >> 4;
    const int wr = wid >> 2, wc = wid & 3;
    const int row0 = blockIdx.x * 128;

    long long asrc; int adst;
    {
        int c = tid, r = c >> 2, s = c & 3;
        int kc = s ^ ((r >> 1) & 3);
        asrc = (long long)min(row0 + r, M - 1) * K + kc * 8;
        adst = c * 16;
    }
    long long bsrc[2]; int bdst[2];
#pragma unroll
    for (int i = 0; i < 2; ++i) {
        int c = wid * 128 + i * 64 + lane, r = c >> 2, s = c & 3;
        int kc = s ^ ((r >> 1) & 3);
        bsrc[i] = (long long)r * K + kc * 8;
        bdst[i] = 8192 + c * 16;
    }

    const int slot = (lg ^ ((l15 >> 1) & 3)) * 16;
    int aoff[4], boff[4];
#pragma unroll
    for (int m = 0; m < 4; ++m) aoff[m] = (wr * 64 + m * 16 + l15) * 64 + slot;
#pragma unroll
    for (int n = 0; n < 4; ++n) boff[n] = 8192 + (wc * 64 + n * 16 + l15) * 64 + slot;

    f32x4 acc[4][4] = {};

    auto stage = [&](int buf, int t) {
        int k0 = t * 32;
        gload16(A  + asrc + k0, &lds[buf][adst]);
        gload16(WT + bsrc[0] + k0, &lds[buf][bdst[0]]);
        gload16(WT + bsrc[1] + k0, &lds[buf][bdst[1]]);
    };

    stage(0, 0);
    __syncthreads();

    for (int t = 0; t < 8; ++t) {
        const int cur = t & 1;
        if (t + 1 < 8) stage(cur ^ 1, t + 1);
        const char* L = lds[cur];
        bf16x8 af[4], bfr[4];
#pragma unroll
        for (int m = 0; m < 4; ++m) af[m]  = *(const bf16x8*)(L + aoff[m]);
#pragma unroll
        for (int n = 0; n < 4; ++n) bfr[n] = *(const bf16x8*)(L + boff[n]);
#pragma unroll
        for (int m = 0; m < 4; ++m)
#pragma unroll
            for (int n = 0; n < 4; ++n)
                acc[m][n] = __builtin_amdgcn_mfma_f32_16x16x32_bf16(af[m], bfr[n], acc[m][n], 0, 0, 0);
        __syncthreads();
    }

    if (wc < 2) {
#pragma unroll
        for (int m = 0; m < 4; ++m)
#pragma unroll
            for (int rr = 0; rr < 4; ++rr) {
                int grow = row0 + wr * 64 + m * 16 + lg * 4 + rr;
                if (grow >= M) continue;
#pragma unroll
                for (int n = 0; n < 4; ++n) {
                    int col = wc * 64 + n * 16 + l15;
                    p2[(long long)grow * 128 + col] = f2bf(acc[m][n][rr]);
                }
            }
    } else {
        float bv[4];
#pragma unroll
        for (int n = 0; n < 4; ++n) bv[n] = b2[(wc - 2) * 64 + n * 16 + l15];
#pragma unroll
        for (int m = 0; m < 4; ++m)
#pragma unroll
            for (int rr = 0; rr < 4; ++rr) {
                int grow = row0 + wr * 64 + m * 16 + lg * 4 + rr;
                if (grow >= M) continue;
#pragma unroll
                for (int n = 0; n < 4; ++n) {
                    int col = (wc - 2) * 64 + n * 16 + l15;
                    self2[(long long)grow * 128 + col] = f2bf(acc[m][n][rr] + bv[n]);
                }
            }
    }
}

// ===== gather128 + final: out = normalize(relu(self2 + mean_nb(p2))) =====
__global__ void gather_final_kernel(const unsigned short* __restrict__ p2, const int* __restrict__ off,
                                    const int* __restrict__ csr, const unsigned short* __restrict__ self2,
                                    float* __restrict__ out, int N) {
    int wid  = (int)((blockIdx.x * (long long)blockDim.x + threadIdx.x) >> 6);
    int lane = threadIdx.x & 63;
    if (wid >= N) return;
    int start = off[wid], end = off[wid + 1];
    const int g  = lane >> 4;
    const int c8 = (lane & 15) * 8;
    float a[8] = {};
    int e = start;
    for (; e + 7 < end; e += 8) {
        int s0 = csr[e + g], s1 = csr[e + 4 + g];
        ushort8v v0 = *(const ushort8v*)(p2 + (long long)s0 * 128 + c8);
        ushort8v v1 = *(const ushort8v*)(p2 + (long long)s1 * 128 + c8);
#pragma unroll
        for (int j = 0; j < 8; ++j) a[j] += bf2f(v0[j]) + bf2f(v1[j]);
    }
    for (; e < end; e += 4) {
        int idx = e + g;
        if (idx < end) {
            int s = csr[idx];
            ushort8v v = *(const ushort8v*)(p2 + (long long)s * 128 + c8);
#pragma unroll
            for (int j = 0; j < 8; ++j) a[j] += bf2f(v[j]);
        }
    }
#pragma unroll
    for (int j = 0; j < 8; ++j) {
        a[j] += __shfl_xor(a[j], 16);
        a[j] += __shfl_xor(a[j], 32);
    }
    float invd = 1.0f / (float)max(end - start, 1);
    ushort8v sv = *(const ushort8v*)(self2 + (long long)wid * 128 + c8);
    float v[8];
    float ss = 0.f;
#pragma unroll
    for (int j = 0; j < 8; ++j) {
        v[j] = fmaxf(bf2f(sv[j]) + a[j] * invd, 0.f);
        ss += v[j] * v[j];
    }
    ss += __shfl_xor(ss, 1);
    ss += __shfl_xor(ss, 2);
    ss += __shfl_xor(ss, 4);
    ss += __shfl_xor(ss, 8);
    float inv = 1.0f / fmaxf(sqrtf(ss), 1e-12f);
    if (g == 0) {
        f32x4 o0 = { v[0] * inv, v[1] * inv, v[2] * inv, v[3] * inv };
        f32x4 o1 = { v[4] * inv, v[5] * inv, v[6] * inv, v[7] * inv };
        float* dstp = out + (long long)wid * 128 + c8;
        __builtin_nontemporal_store(o0, (f32x4*)dstp);     // final output: never re-read
        __builtin_nontemporal_store(o1, (f32x4*)(dstp + 4));
    }
}

extern "C" void kernel_launch(void* const* d_in, const int* in_sizes, int n_in,
                              void* d_out, int out_size, void* d_ws, size_t ws_size,
                              hipStream_t stream) {
    const float* feat     = (const float*)d_in[0];
    const int*   src      = (const int*)  d_in[1];
    const int*   dst      = (const int*)  d_in[2];
    const float* w_self1  = (const float*)d_in[3];
    const float* w_neigh1 = (const float*)d_in[4];
    const float* b1       = (const float*)d_in[5];
    const float* w_self2  = (const float*)d_in[6];
    const float* w_neigh2 = (const float*)d_in[7];
    const float* b2       = (const float*)d_in[8];
    float* out = (float*)d_out;

    const int N = in_sizes[0] / DIN;    // 100000
    const int E = in_sizes[1];          // 800000

    char* ws = (char*)d_ws;
    auto a4k = [](size_t x) { return (x + 4095) & ~(size_t)4095; };
    size_t o = 0;
    int* cnt    = (int*)(ws + o); o += (size_t)N * 4;                 // cnt then status: one memset
    int* status = (int*)(ws + o); o = a4k(o + 128 * 4);
    int* off  = (int*)(ws + o); o += a4k((size_t)(N + 1) * 4);
    int* part = (int*)(ws + o); o += a4k(1024);                       // agg[128] + incl[128]
    int* csr  = (int*)(ws + o); o += a4k((size_t)E * 4);
    unsigned short* ws1t = (unsigned short*)(ws + o); o += a4k((size_t)DIN * DH * 2);
    unsigned short* wn1t = (unsigned short*)(ws + o); o += a4k((size_t)DIN * DH * 2);
    unsigned short* wcat = (unsigned short*)(ws + o); o += a4k((size_t)256 * 256 * 2);
    unsigned int*   feat8 = (unsigned int*)(ws + o); o += a4k((size_t)N * DIN);       // fp8 mirror
    unsigned short* featb = (unsigned short*)(ws + o); o += a4k((size_t)N * DIN * 2);  // reused: p2b
    unsigned short* aggb  = (unsigned short*)(ws + o); o += a4k((size_t)N * DIN * 2);  // reused: self2b
    unsigned short* h1b   = (unsigned short*)(ws + o); o += a4k((size_t)N * DH * 2);

    int* aggbuf  = part;
    int* inclbuf = part + 128;

    unsigned short* p2b    = featb;   // dead after gemm1
    unsigned short* self2b = aggb;    // dead after gemm1

    const int nblk = (N + 1023) / 1024;   // 98

    // cvt geometry: ncHalf work units, 256 per block; split A/B
    long long ncHalf = (long long)N * DIN / 8;      // 3.2e6
    const int bCvtTot = (int)((ncHalf + 255) / 256);   // 12500
    const int bCvtA = 5500;
    const int bCvtB = bCvtTot - bCvtA;              // 7000
    const int bAtom = (E + 255) / 256;              // 3125 (count and fill)
    const int bWt   = 768;

    // ---- A: count interleaved with cvt[0, bCvtA) (cnt + status zeroed first) ----
    hipMemsetAsync(cnt, 0, ((size_t)N + 128) * 4, stream);
    const int nA = bCvtA + bAtom;                   // 8625
    countcvt_kernel<<<nA, 256, 0, stream>>>(dst, cnt, E, bAtom, feat, featb, feat8, ncHalf, nA);

    // ---- single-pass CSR scan (decoupled lookback) ----
    scan_lookback_kernel<<<nblk, 256, 0, stream>>>(cnt, status, aggbuf, inclbuf, off, N, E, nblk);

    // ---- B: fill interleaved with cvt[bCvtA, end) + wtrans ----
    const int nB = bCvtB + bWt + bAtom;             // 10893
    fillcvt_kernel<<<nB, 256, 0, stream>>>(
        src, dst, cnt, csr, E, bAtom,
        feat, featb, feat8, ncHalf, bCvtA, bCvtB,
        w_self1, w_neigh1, w_self2, w_neigh2, ws1t, wn1t, wcat, nB);

    const int mblk = (N + 127) / 128;   // 782

    // ---- layer 1: fp8 gather + bf16 MFMA GEMM ----
    gather_mean256_kernel<<<(N + 3) / 4, 256, 0, stream>>>(feat8, off, csr, aggb, N);
    gemm1_kernel<<<mblk, 512, 0, stream>>>(featb, ws1t, aggb, wn1t, b1, h1b, N);

    // ---- layer 2: both projections in one pass, then fused gather+norm ----
    gemm23_kernel<<<mblk, 512, 0, stream>>>(h1b, wcat, b2, p2b, self2b, N);
    gather_final_kernel<<<(N + 3) / 4, 256, 0, stream>>>(p2b, off, csr, self2b, out, N);
}

// Round 19
// 255.162 us; speedup vs baseline: 1.1102x; 1.1102x over previous
//
#include <hip/hip_runtime.h>

#define DIN 256
#define DH  256
#define DOUT 128

typedef __attribute__((ext_vector_type(8))) short bf16x8;
typedef __attribute__((ext_vector_type(4))) float f32x4;
typedef __attribute__((ext_vector_type(2))) float f32x2;
typedef __attribute__((ext_vector_type(4))) unsigned short ushort4v;
typedef __attribute__((ext_vector_type(8))) unsigned short ushort8v;
typedef __attribute__((ext_vector_type(4))) unsigned int uint4v;

static __device__ __forceinline__ unsigned short f2bf(float x) {
    unsigned u = __float_as_uint(x);
    u += 0x7fffu + ((u >> 16) & 1u);          // round-to-nearest-even
    return (unsigned short)(u >> 16);
}
static __device__ __forceinline__ float bf2f(unsigned short h) {
    return __uint_as_float(((unsigned)h) << 16);
}

static __device__ __forceinline__ void gload16(const unsigned short* g, void* l) {
    __builtin_amdgcn_global_load_lds(
        (const __attribute__((address_space(1))) unsigned int*)g,
        (__attribute__((address_space(3))) unsigned int*)l,
        16, 0, 0);
}

// cvt work unit: thread handles f32x4 chunks i and i+ncHalf (MLP=2, coalesced)
static __device__ __forceinline__ void cvt_unit(const float* __restrict__ feat,
                                                unsigned short* __restrict__ featb,
                                                unsigned int* __restrict__ feat8,
                                                long long i, long long ncHalf) {
    long long i2 = i + ncHalf;
    f32x4 v0 = __builtin_nontemporal_load((const f32x4*)feat + i);
    f32x4 v1 = __builtin_nontemporal_load((const f32x4*)feat + i2);
    ushort4v o0, o1;
    o0[0] = f2bf(v0[0]); o0[1] = f2bf(v0[1]); o0[2] = f2bf(v0[2]); o0[3] = f2bf(v0[3]);
    o1[0] = f2bf(v1[0]); o1[1] = f2bf(v1[1]); o1[2] = f2bf(v1[2]); o1[3] = f2bf(v1[3]);
    *((ushort4v*)featb + i)  = o0;          // plain: cached for gemm1
    *((ushort4v*)featb + i2) = o1;
    int u0 = __builtin_amdgcn_cvt_pk_fp8_f32(v0[0], v0[1], 0, 0);
    u0     = __builtin_amdgcn_cvt_pk_fp8_f32(v0[2], v0[3], u0, 1);
    int u1 = __builtin_amdgcn_cvt_pk_fp8_f32(v1[0], v1[1], 0, 0);
    u1     = __builtin_amdgcn_cvt_pk_fp8_f32(v1[2], v1[3], u1, 1);
    feat8[i]  = (unsigned)u0;               // plain: must stay L2/L3-hot for gather
    feat8[i2] = (unsigned)u1;
}

// ==== A: degree-count blocks Bresenham-interleaved among cvt[0, bCvtA) blocks ====
__global__ void countcvt_kernel(const int* __restrict__ dst, int* __restrict__ cnt, int E, int bCnt,
                                const float* __restrict__ feat, unsigned short* __restrict__ featb,
                                unsigned int* __restrict__ feat8, long long ncHalf, int nA) {
    int b = blockIdx.x;
    int t0 = (int)((long long)b * bCnt / nA);
    int t1 = (int)((long long)(b + 1) * bCnt / nA);
    if (t1 > t0) {
        int e = t0 * 256 + threadIdx.x;
        if (e < E) atomicAdd(&cnt[dst[e]], 1);
    } else {
        long long i = (long long)(b - t0) * 256 + threadIdx.x;
        if (i < ncHalf) cvt_unit(feat, featb, feat8, i, ncHalf);
    }
}

// ==== B: fill-csr blocks Bresenham-interleaved among cvt[bCvtA, 12500) + wtrans blocks ====
__global__ void fillcvt_kernel(const int* __restrict__ src, const int* __restrict__ dst,
                               int* __restrict__ cursor, int* __restrict__ csr, int E, int bFill,
                               const float* __restrict__ feat, unsigned short* __restrict__ featb,
                               unsigned int* __restrict__ feat8, long long ncHalf,
                               int cvtOff, int bCvtB,
                               const float* __restrict__ w_self1, const float* __restrict__ w_neigh1,
                               const float* __restrict__ w_self2, const float* __restrict__ w_neigh2,
                               unsigned short* __restrict__ ws1t, unsigned short* __restrict__ wn1t,
                               unsigned short* __restrict__ wcat, int nB) {
    int b = blockIdx.x;
    int t0 = (int)((long long)b * bFill / nB);
    int t1 = (int)((long long)(b + 1) * bFill / nB);
    if (t1 > t0) {
        int e = t0 * 256 + threadIdx.x;
        if (e < E) {
            int d = dst[e];
            int p = atomicAdd(&cursor[d], 1);
            csr[p] = src[e];
        }
    } else {
        int j = b - t0;
        if (j < bCvtB) {
            long long i = (long long)(cvtOff + j) * 256 + threadIdx.x;
            if (i < ncHalf) cvt_unit(feat, featb, feat8, i, ncHalf);
        } else {
            int idx = (j - bCvtB) * 256 + threadIdx.x;
            if (idx < 65536) {                      // ws1t[n][k] = w_self1[k][n]
                int nn = idx >> 8, k = idx & 255;
                ws1t[idx] = f2bf(w_self1[k * 256 + nn]);
            } else if (idx < 131072) {              // wn1t
                int jj = idx - 65536; int nn = jj >> 8, k = jj & 255;
                wn1t[jj] = f2bf(w_neigh1[k * 256 + nn]);
            } else if (idx < 163840) {              // wcat rows 0..127 = wn2^T
                int jj = idx - 131072; int nn = jj >> 8, k = jj & 255;
                wcat[jj] = f2bf(w_neigh2[k * 128 + nn]);
            } else if (idx < 196608) {              // wcat rows 128..255 = ws2^T
                int jj = idx - 163840; int nn = jj >> 8, k = jj & 255;
                wcat[32768 + jj] = f2bf(w_self2[k * 128 + nn]);
            }
        }
    }
}

// ================= CSR scan =================
__global__ void block_sums_kernel(const int* __restrict__ cnt, int* __restrict__ partial, int N) {
    __shared__ int sdata[256];
    int t = threadIdx.x;
    int base = blockIdx.x * 1024;
    int s = 0;
#pragma unroll
    for (int j = 0; j < 4; ++j) {
        int i = base + t * 4 + j;
        if (i < N) s += cnt[i];
    }
    sdata[t] = s; __syncthreads();
    for (int o = 128; o; o >>= 1) {
        if (t < o) sdata[t] += sdata[t + o];
        __syncthreads();
    }
    if (t == 0) partial[blockIdx.x] = sdata[0];
}

// fused: scans the (<=256) partials locally, then writes offsets AND inits cursor
__global__ void scan_block_kernel(int* __restrict__ cnt, const int* __restrict__ partial,
                                  int* __restrict__ off, int N, int E, int nb) {
    __shared__ int sdata[256];
    __shared__ int pbase;
    int b = blockIdx.x, t = threadIdx.x;

    int pv = (t < nb) ? partial[t] : 0;
    sdata[t] = pv; __syncthreads();
    for (int o = 1; o < 256; o <<= 1) {
        int y = (t >= o) ? sdata[t - o] : 0;
        __syncthreads();
        sdata[t] += y;
        __syncthreads();
    }
    if (t == 0) pbase = (b == 0) ? 0 : sdata[b - 1];
    __syncthreads();
    int base0 = pbase;
    __syncthreads();

    int base = b * 1024;
    int vals[4]; int local = 0;
#pragma unroll
    for (int j = 0; j < 4; ++j) {
        int i = base + t * 4 + j;
        vals[j] = (i < N) ? cnt[i] : 0;
        local += vals[j];
    }
    sdata[t] = local; __syncthreads();
    for (int o = 1; o < 256; o <<= 1) {
        int y = (t >= o) ? sdata[t - o] : 0;
        __syncthreads();
        sdata[t] += y;
        __syncthreads();
    }
    int run = sdata[t] - local + base0;
#pragma unroll
    for (int j = 0; j < 4; ++j) {
        int i = base + t * 4 + j;
        if (i < N) { off[i] = run; cnt[i] = run; }   // cnt becomes cursor
        run += vals[j];
    }
    if (b == 0 && t == 0) off[N] = E;
}

// ===== gather-mean D=256 from fp8: 4 rows per load (16 lanes each, 16B/lane) =====
__global__ void gather_mean256_kernel(const unsigned int* __restrict__ feat8, const int* __restrict__ off,
                                      const int* __restrict__ csr, unsigned short* __restrict__ agg, int N) {
    int wid  = (int)((blockIdx.x * (long long)blockDim.x + threadIdx.x) >> 6);
    int lane = threadIdx.x & 63;
    if (wid >= N) return;
    int start = off[wid], end = off[wid + 1];
    const int g   = lane >> 4;
    const int cl  = lane & 15;
    float a[16] = {};
    int e = start;
    for (; e + 7 < end; e += 8) {
        int s0 = csr[e + g], s1 = csr[e + 4 + g];
        uint4v v0 = *(const uint4v*)(feat8 + (long long)s0 * 64 + cl * 4);
        uint4v v1 = *(const uint4v*)(feat8 + (long long)s1 * 64 + cl * 4);
#pragma unroll
        for (int d = 0; d < 4; ++d) {
            f32x2 p0 = __builtin_amdgcn_cvt_pk_f32_fp8((int)v0[d], false);
            f32x2 p1 = __builtin_amdgcn_cvt_pk_f32_fp8((int)v0[d], true);
            f32x2 q0 = __builtin_amdgcn_cvt_pk_f32_fp8((int)v1[d], false);
            f32x2 q1 = __builtin_amdgcn_cvt_pk_f32_fp8((int)v1[d], true);
            a[d * 4 + 0] += p0[0] + q0[0];
            a[d * 4 + 1] += p0[1] + q0[1];
            a[d * 4 + 2] += p1[0] + q1[0];
            a[d * 4 + 3] += p1[1] + q1[1];
        }
    }
    for (; e < end; e += 4) {
        int idx = e + g;
        if (idx < end) {
            int s = csr[idx];
            uint4v v = *(const uint4v*)(feat8 + (long long)s * 64 + cl * 4);
#pragma unroll
            for (int d = 0; d < 4; ++d) {
                f32x2 p0 = __builtin_amdgcn_cvt_pk_f32_fp8((int)v[d], false);
                f32x2 p1 = __builtin_amdgcn_cvt_pk_f32_fp8((int)v[d], true);
                a[d * 4 + 0] += p0[0];
                a[d * 4 + 1] += p0[1];
                a[d * 4 + 2] += p1[0];
                a[d * 4 + 3] += p1[1];
            }
        }
    }
#pragma unroll
    for (int j = 0; j < 16; ++j) {
        a[j] += __shfl_xor(a[j], 16);
        a[j] += __shfl_xor(a[j], 32);
    }
    if (g == 0) {
        float inv = 1.0f / (float)max(end - start, 1);
        ushort8v o0, o1;
#pragma unroll
        for (int j = 0; j < 8; ++j) { o0[j] = f2bf(a[j] * inv); o1[j] = f2bf(a[8 + j] * inv); }
        unsigned short* dstp = agg + (long long)wid * 256 + cl * 16;
        *(ushort8v*)dstp       = o0;   // plain store: agg read by gemm1 next
        *(ushort8v*)(dstp + 8) = o1;
    }
}

// ================= GEMM 1: h1 = relu(feat@Ws1 + agg@Wn1 + b1) =================
__global__ __launch_bounds__(512)
void gemm1_kernel(const unsigned short* __restrict__ A,  const unsigned short* __restrict__ WT,
                  const unsigned short* __restrict__ A2, const unsigned short* __restrict__ WT2,
                  const float* __restrict__ bias, unsigned short* __restrict__ C, int M)
{
    const int K = 256;
    __shared__ __align__(16) char lds[2][24576];   // A: [0,8192)  B: [8192,24576)

    const int tid = threadIdx.x;
    const int wid = tid >> 6, lane = tid & 63;
    const int l15 = lane & 15, lg = lane >> 4;
    const int wr = wid >> 2, wc = wid & 3;
    const int row0 = blockIdx.x * 128;

    long long asrc; int adst;
    {
        int c = tid, r = c >> 2, s = c & 3;
        int kc = s ^ ((r >> 1) & 3);
        asrc = (long long)min(row0 + r, M - 1) * K + kc * 8;
        adst = c * 16;
    }
    long long bsrc[2]; int bdst[2];
#pragma unroll
    for (int i = 0; i < 2; ++i) {
        int c = wid * 128 + i * 64 + lane, r = c >> 2, s = c & 3;
        int kc = s ^ ((r >> 1) & 3);
        bsrc[i] = (long long)r * K + kc * 8;
        bdst[i] = 8192 + c * 16;
    }

    const int slot = (lg ^ ((l15 >> 1) & 3)) * 16;
    int aoff[4], boff[4];
#pragma unroll
    for (int m = 0; m < 4; ++m) aoff[m] = (wr * 64 + m * 16 + l15) * 64 + slot;
#pragma unroll
    for (int n = 0; n < 4; ++n) boff[n] = 8192 + (wc * 64 + n * 16 + l15) * 64 + slot;

    f32x4 acc[4][4] = {};

    auto stage = [&](int buf, int t) {
        const unsigned short* Ap = (t >= 8) ? A2 : A;
        const unsigned short* Wp = (t >= 8) ? WT2 : WT;
        int k0 = (t & 7) * 32;
        gload16(Ap + asrc + k0, &lds[buf][adst]);
        gload16(Wp + bsrc[0] + k0, &lds[buf][bdst[0]]);
        gload16(Wp + bsrc[1] + k0, &lds[buf][bdst[1]]);
    };

    stage(0, 0);
    __syncthreads();

    for (int t = 0; t < 16; ++t) {
        const int cur = t & 1;
        if (t + 1 < 16) stage(cur ^ 1, t + 1);
        const char* L = lds[cur];
        bf16x8 af[4], bfr[4];
#pragma unroll
        for (int m = 0; m < 4; ++m) af[m]  = *(const bf16x8*)(L + aoff[m]);
#pragma unroll
        for (int n = 0; n < 4; ++n) bfr[n] = *(const bf16x8*)(L + boff[n]);
#pragma unroll
        for (int m = 0; m < 4; ++m)
#pragma unroll
            for (int n = 0; n < 4; ++n)
                acc[m][n] = __builtin_amdgcn_mfma_f32_16x16x32_bf16(af[m], bfr[n], acc[m][n], 0, 0, 0);
        __syncthreads();
    }

#pragma unroll
    for (int m = 0; m < 4; ++m) {
#pragma unroll
        for (int rr = 0; rr < 4; ++rr) {
            int grow = row0 + wr * 64 + m * 16 + lg * 4 + rr;
            if (grow >= M) continue;
#pragma unroll
            for (int n = 0; n < 4; ++n) {
                int gcol = wc * 64 + n * 16 + l15;
                float v = fmaxf(acc[m][n][rr] + bias[gcol], 0.f);
                C[(long long)grow * 256 + gcol] = f2bf(v);
            }
        }
    }
}

// ====== GEMM 23: [p2 | self2+b2] = h1 @ wcat^T  (single K=256 pass, split epilogue) ======
__global__ __launch_bounds__(512)
void gemm23_kernel(const unsigned short* __restrict__ A, const unsigned short* __restrict__ WT,
                   const float* __restrict__ b2,
                   unsigned short* __restrict__ p2, unsigned short* __restrict__ self2, int M)
{
    const int K = 256;
    __shared__ __align__(16) char lds[2][24576];   // A: [0,8192)  B: [8192,24576)

    const int tid = threadIdx.x;
    const int wid = tid >> 6, lane = tid & 63;
    const int l15 = lane & 15, lg = lane >> 4;
    const int wr = wid >> 2, wc = wid & 3;
    const int row0 = blockIdx.x * 128;

    long long asrc; int adst;
    {
        int c = tid, r = c >> 2, s = c & 3;
        int kc = s ^ ((r >> 1) & 3);
        asrc = (long long)min(row0 + r, M - 1) * K + kc * 8;
        adst = c * 16;
    }
    long long bsrc[2]; int bdst[2];
#pragma unroll
    for (int i = 0; i < 2; ++i) {
        int c = wid * 128 + i * 64 + lane, r = c >> 2, s = c & 3;
        int kc = s ^ ((r >> 1) & 3);
        bsrc[i] = (long long)r * K + kc * 8;
        bdst[i] = 8192 + c * 16;
    }

    const int slot = (lg ^ ((l15 >> 1) & 3)) * 16;
    int aoff[4], boff[4];
#pragma unroll
    for (int m = 0; m < 4; ++m) aoff[m] = (wr * 64 + m * 16 + l15) * 64 + slot;
#pragma unroll
    for (int n = 0; n < 4; ++n) boff[n] = 8192 + (wc * 64 + n * 16 + l15) * 64 + slot;

    f32x4 acc[4][4] = {};

    auto stage = [&](int buf, int t) {
        int k0 = t * 32;
        gload16(A  + asrc + k0, &lds[buf][adst]);
        gload16(WT + bsrc[0] + k0, &lds[buf][bdst[0]]);
        gload16(WT + bsrc[1] + k0, &lds[buf][bdst[1]]);
    };

    stage(0, 0);
    __syncthreads();

    for (int t = 0; t < 8; ++t) {
        const int cur = t & 1;
        if (t + 1 < 8) stage(cur ^ 1, t + 1);
        const char* L = lds[cur];
        bf16x8 af[4], bfr[4];
#pragma unroll
        for (int m = 0; m < 4; ++m) af[m]  = *(const bf16x8*)(L + aoff[m]);
#pragma unroll
        for (int n = 0; n < 4; ++n) bfr[n] = *(const bf16x8*)(L + boff[n]);
#pragma unroll
        for (int m = 0; m < 4; ++m)
#pragma unroll
            for (int n = 0; n < 4; ++n)
                acc[m][n] = __builtin_amdgcn_mfma_f32_16x16x32_bf16(af[m], bfr[n], acc[m][n], 0, 0, 0);
        __syncthreads();
    }

    if (wc < 2) {
#pragma unroll
        for (int m = 0; m < 4; ++m)
#pragma unroll
            for (int rr = 0; rr < 4; ++rr) {
                int grow = row0 + wr * 64 + m * 16 + lg * 4 + rr;
                if (grow >= M) continue;
#pragma unroll
                for (int n = 0; n < 4; ++n) {
                    int col = wc * 64 + n * 16 + l15;
                    p2[(long long)grow * 128 + col] = f2bf(acc[m][n][rr]);
                }
            }
    } else {
        float bv[4];
#pragma unroll
        for (int n = 0; n < 4; ++n) bv[n] = b2[(wc - 2) * 64 + n * 16 + l15];
#pragma unroll
        for (int m = 0; m < 4; ++m)
#pragma unroll
            for (int rr = 0; rr < 4; ++rr) {
                int grow = row0 + wr * 64 + m * 16 + lg * 4 + rr;
                if (grow >= M) continue;
#pragma unroll
                for (int n = 0; n < 4; ++n) {
                    int col = (wc - 2) * 64 + n * 16 + l15;
                    self2[(long long)grow * 128 + col] = f2bf(acc[m][n][rr] + bv[n]);
                }
            }
    }
}

// ===== gather128 + final: out = normalize(relu(self2 + mean_nb(p2))) =====
__global__ void gather_final_kernel(const unsigned short* __restrict__ p2, const int* __restrict__ off,
                                    const int* __restrict__ csr, const unsigned short* __restrict__ self2,
                                    float* __restrict__ out, int N) {
    int wid  = (int)((blockIdx.x * (long long)blockDim.x + threadIdx.x) >> 6);
    int lane = threadIdx.x & 63;
    if (wid >= N) return;
    int start = off[wid], end = off[wid + 1];
    const int g  = lane >> 4;
    const int c8 = (lane & 15) * 8;
    // issue self2 row load EARLY: latency hides under the p2 gather loop
    ushort8v sv = *(const ushort8v*)(self2 + (long long)wid * 128 + c8);
    float a[8] = {};
    int e = start;
    for (; e + 7 < end; e += 8) {
        int s0 = csr[e + g], s1 = csr[e + 4 + g];
        ushort8v v0 = *(const ushort8v*)(p2 + (long long)s0 * 128 + c8);
        ushort8v v1 = *(const ushort8v*)(p2 + (long long)s1 * 128 + c8);
#pragma unroll
        for (int j = 0; j < 8; ++j) a[j] += bf2f(v0[j]) + bf2f(v1[j]);
    }
    for (; e < end; e += 4) {
        int idx = e + g;
        if (idx < end) {
            int s = csr[idx];
            ushort8v v = *(const ushort8v*)(p2 + (long long)s * 128 + c8);
#pragma unroll
            for (int j = 0; j < 8; ++j) a[j] += bf2f(v[j]);
        }
    }
#pragma unroll
    for (int j = 0; j < 8; ++j) {
        a[j] += __shfl_xor(a[j], 16);
        a[j] += __shfl_xor(a[j], 32);
    }
    float invd = 1.0f / (float)max(end - start, 1);
    float v[8];
    float ss = 0.f;
#pragma unroll
    for (int j = 0; j < 8; ++j) {
        v[j] = fmaxf(bf2f(sv[j]) + a[j] * invd, 0.f);
        ss += v[j] * v[j];
    }
    ss += __shfl_xor(ss, 1);
    ss += __shfl_xor(ss, 2);
    ss += __shfl_xor(ss, 4);
    ss += __shfl_xor(ss, 8);
    float inv = 1.0f / fmaxf(sqrtf(ss), 1e-12f);
    if (g == 0) {
        f32x4 o0 = { v[0] * inv, v[1] * inv, v[2] * inv, v[3] * inv };
        f32x4 o1 = { v[4] * inv, v[5] * inv, v[6] * inv, v[7] * inv };
        float* dstp = out + (long long)wid * 128 + c8;
        __builtin_nontemporal_store(o0, (f32x4*)dstp);     // final output: never re-read
        __builtin_nontemporal_store(o1, (f32x4*)(dstp + 4));
    }
}

extern "C" void kernel_launch(void* const* d_in, const int* in_sizes, int n_in,
                              void* d_out, int out_size, void* d_ws, size_t ws_size,
                              hipStream_t stream) {
    const float* feat     = (const float*)d_in[0];
    const int*   src      = (const int*)  d_in[1];
    const int*   dst      = (const int*)  d_in[2];
    const float* w_self1  = (const float*)d_in[3];
    const float* w_neigh1 = (const float*)d_in[4];
    const float* b1       = (const float*)d_in[5];
    const float* w_self2  = (const float*)d_in[6];
    const float* w_neigh2 = (const float*)d_in[7];
    const float* b2       = (const float*)d_in[8];
    float* out = (float*)d_out;

    const int N = in_sizes[0] / DIN;    // 100000
    const int E = in_sizes[1];          // 800000

    char* ws = (char*)d_ws;
    auto a4k = [](size_t x) { return (x + 4095) & ~(size_t)4095; };
    size_t o = 0;
    int* cnt  = (int*)(ws + o); o += a4k((size_t)N * 4);
    int* off  = (int*)(ws + o); o += a4k((size_t)(N + 1) * 4);
    int* part = (int*)(ws + o); o += a4k(1024);
    int* csr  = (int*)(ws + o); o += a4k((size_t)E * 4);
    unsigned short* ws1t = (unsigned short*)(ws + o); o += a4k((size_t)DIN * DH * 2);
    unsigned short* wn1t = (unsigned short*)(ws + o); o += a4k((size_t)DIN * DH * 2);
    unsigned short* wcat = (unsigned short*)(ws + o); o += a4k((size_t)256 * 256 * 2);
    unsigned int*   feat8 = (unsigned int*)(ws + o); o += a4k((size_t)N * DIN);       // fp8 mirror
    unsigned short* featb = (unsigned short*)(ws + o); o += a4k((size_t)N * DIN * 2);  // reused: p2b
    unsigned short* aggb  = (unsigned short*)(ws + o); o += a4k((size_t)N * DIN * 2);  // reused: self2b
    unsigned short* h1b   = (unsigned short*)(ws + o); o += a4k((size_t)N * DH * 2);

    unsigned short* p2b    = featb;   // dead after gemm1
    unsigned short* self2b = aggb;    // dead after gemm1

    const int nblk = (N + 1023) / 1024;   // 98

    // cvt geometry: ncHalf work units, 256 per block -> 12500 cvt blocks total, split A/B
    long long ncHalf = (long long)N * DIN / 8;      // 3.2e6
    const int bCvtTot = (int)((ncHalf + 255) / 256);   // 12500
    const int bCvtA = 7000;
    const int bCvtB = bCvtTot - bCvtA;              // 5500
    const int bAtom = (E + 255) / 256;              // 3125 (count and fill)
    const int bWt   = 768;

    // ---- A: count interleaved with cvt[0, bCvtA) ----
    hipMemsetAsync(cnt, 0, (size_t)N * 4, stream);
    const int nA = bCvtA + bAtom;                   // 10125
    countcvt_kernel<<<nA, 256, 0, stream>>>(dst, cnt, E, bAtom, feat, featb, feat8, ncHalf, nA);

    // ---- CSR scans ----
    block_sums_kernel<<<nblk, 256, 0, stream>>>(cnt, part, N);
    scan_block_kernel<<<nblk, 256, 0, stream>>>(cnt, part, off, N, E, nblk);

    // ---- B: fill interleaved with cvt[bCvtA, 12500) + wtrans ----
    const int nB = bCvtB + bWt + bAtom;             // 9393
    fillcvt_kernel<<<nB, 256, 0, stream>>>(
        src, dst, cnt, csr, E, bAtom,
        feat, featb, feat8, ncHalf, bCvtA, bCvtB,
        w_self1, w_neigh1, w_self2, w_neigh2, ws1t, wn1t, wcat, nB);

    const int mblk = (N + 127) / 128;   // 782

    // ---- layer 1: fp8 gather + bf16 MFMA GEMM ----
    gather_mean256_kernel<<<(N + 3) / 4, 256, 0, stream>>>(feat8, off, csr, aggb, N);
    gemm1_kernel<<<mblk, 512, 0, stream>>>(featb, ws1t, aggb, wn1t, b1, h1b, N);

    // ---- layer 2: both projections in one pass, then fused gather+norm ----
    gemm23_kernel<<<mblk, 512, 0, stream>>>(h1b, wcat, b2, p2b, self2b, N);
    gather_final_kernel<<<(N + 3) / 4, 256, 0, stream>>>(p2b, off, csr, self2b, out, N);
}